// Round 14
// baseline (80.538 us; speedup 1.0000x reference)
//
#include <hip/hip_runtime.h>
#include <math.h>

#define NB 4
#define HH 16
#define SS 1024
#define DD 64
#define NKST 16   // SS / 64

typedef __attribute__((ext_vector_type(8))) short bf16x8;
typedef __attribute__((ext_vector_type(4))) float f32x4;

static __device__ __forceinline__ short f2bf(float f) {
    __bf16 h = (__bf16)f;
    return __builtin_bit_cast(short, h);
}
static __device__ __forceinline__ float bflo(int w) {
    return __builtin_bit_cast(float, (unsigned)w << 16);
}
static __device__ __forceinline__ float bfhi(int w) {
    return __builtin_bit_cast(float, (unsigned)w & 0xffff0000u);
}
static __device__ __forceinline__ float bfu(unsigned short u) {
    return __builtin_bit_cast(float, (unsigned)u << 16);
}
// P LDS: [pos = q*64 + k][8 u32 head-pairs], XOR swizzle (validated R5-R12).
static __device__ __forceinline__ int pidx(int pos, int hp) {
    int s = ((pos >> 2) & 3) | (((pos >> 9) & 1) << 2);
    return pos * 8 + (hp ^ s);
}
// M LDS: [16 g][16 q x 32 k-pairs u32], XOR on 16B groups (validated).
static __device__ __forceinline__ int midx(int g, int loc, int x3) {
    return g * 512 + ((((loc >> 2) ^ x3) << 2) | (loc & 3));
}

static __device__ __forceinline__ bf16x8 load8_bf16(const float* p) {
    const float4* p4 = reinterpret_cast<const float4*>(p);
    float4 a = p4[0], b = p4[1];
    bf16x8 f;
    f[0]=f2bf(a.x); f[1]=f2bf(a.y); f[2]=f2bf(a.z); f[3]=f2bf(a.w);
    f[4]=f2bf(b.x); f[5]=f2bf(b.y); f[6]=f2bf(b.z); f[7]=f2bf(b.w);
    return f;
}

// ---------- merged prep: LDS-staged coalesced; K and V -> frag-major bf16 ----------
__global__ __launch_bounds__(256) void prep_all(const float* __restrict__ xk,
                                                short* __restrict__ kfr,
                                                const float* __restrict__ xv,
                                                short* __restrict__ vfr) {
    __shared__ float T[64][65];
    const int bid = blockIdx.x;
    const int t = threadIdx.x;
    const bool isK = bid < 1024;
    const int tile = isK ? bid : bid - 1024;     // (b*16+h)*16 + kst
    const float* src = (isK ? xk : xv) + ((size_t)(tile >> 4) * SS + (tile & 15) * 64) * DD;
    int row = t >> 2, col = (t & 3) * 16;
#pragma unroll
    for (int ii = 0; ii < 4; ++ii) {
        float4 v = *reinterpret_cast<const float4*>(src + row * DD + col + ii * 4);
        T[row][col + ii*4] = v.x; T[row][col + ii*4 + 1] = v.y;
        T[row][col + ii*4 + 2] = v.z; T[row][col + ii*4 + 3] = v.w;
    }
    __syncthreads();
    if (isK) {
#pragma unroll
        for (int jj = 0; jj < 2; ++jj) {
            int c2 = t * 2 + jj;                  // (kt*2+ds)*64 + lane
            int lane = c2 & 63, ds = (c2 >> 6) & 1, kt = (c2 >> 7) & 3;
            bf16x8 o;
#pragma unroll
            for (int i = 0; i < 8; ++i)
                o[i] = f2bf(T[kt * 16 + (lane & 15)][ds * 32 + (lane >> 4) * 8 + i]);
            *(reinterpret_cast<bf16x8*>(kfr) + (size_t)tile * 512 + c2) = o;
        }
    } else {
#pragma unroll
        for (int jj = 0; jj < 2; ++jj) {
            int c2 = t * 2 + jj;                  // (kc*4+nt)*64 + lane
            int lane = c2 & 63, nt = (c2 >> 6) & 3, kc = (c2 >> 8) & 1;
            bf16x8 o;
#pragma unroll
            for (int i = 0; i < 8; ++i)
                o[i] = f2bf(T[kc * 32 + (lane >> 4) * 8 + i][nt * 16 + (lane & 15)]);
            *(reinterpret_cast<bf16x8*>(vfr) + (size_t)tile * 512 + c2) = o;
        }
    }
}

// One block = (b, qt, kpar), 16 waves, LDS 96KB (P 32K single + M 2x32K dbuf).
// SOFTWARE-PIPELINED, 2 barriers/step, every barrier interval mixes pipes:
//   iter i: [b1 | mix(s_i)->M[i&1] ; softmax+PV(s_{i-1}) from M[(i-1)&1] | b2 |
//            QK^T(s_{i+1})->P ; V-pair prefetch(s_i)]
// (R12's phase-locked form ran all waves in the same phase -> step time was the
//  SUM of pipe busy times. This interleaves VMEM/LDS/VALU/MFMA per interval.)
// Phase1 is 1 head/wave (qf 8 regs, P written as b16 halves) to fit 64 VGPR.
__global__ __launch_bounds__(1024) void hca_fused(
    const float* __restrict__ xq, const short* __restrict__ kfr,
    const short* __restrict__ vfr, const float* __restrict__ Wm,
    const int* __restrict__ causalp, unsigned short* __restrict__ ppO,
    float2* __restrict__ ppml)
{
    __shared__ int Pbuf[8192];       // 32 KB
    __shared__ int Mbuf[2][8192];    // 64 KB

    const int tid  = threadIdx.x;
    const int lane = tid & 63;
    const int w    = tid >> 6;     // 0..15
    const int l15  = lane & 15;
    const int lg   = lane >> 4;

    const int bid  = blockIdx.x;
    const int b    = bid & 3;              // b fixed per XCD
    const int u    = (bid >> 2) & 63;
    const int r    = (bid >> 8) & 1;
    const int qt   = r ? u : 63 - u;
    const int kpar = u & 1;
    const int q0   = qt << 4;
    const int pairIdx = b * 64 + qt;

    const int causal = causalp[0];
    const int h = w;               // phase-1 head (one per wave)
    const int g = w;               // phase-2 output head

    const float LOG2E = 1.44269504088896f;

    bf16x8 wt = {0,0,0,0,0,0,0,0};
    if (lg < 2) {
#pragma unroll
        for (int ii = 0; ii < 8; ++ii)
            wt[ii] = f2bf(Wm[l15 * 16 + lg * 8 + ii] * 0.125f * LOG2E);
    }

    const short* kb0 = kfr + (size_t)(b * HH + h) * NKST * 4096 + lane * 8;
    const short* vb0 = vfr + (size_t)(b * HH + g) * NKST * 4096 + lane * 8;

    // Q A-frag for the single phase-1 head (8 regs)
    bf16x8 qf[2];
    {
        const float* qp = xq + ((size_t)(b * HH + h) * SS + q0 + l15) * DD + lg * 8;
        qf[0] = load8_bf16(qp);
        qf[1] = load8_bf16(qp + 32);
    }

    f32x4 oacc[4];
#pragma unroll
    for (int nt = 0; nt < 4; ++nt) oacc[nt] = (f32x4){0.f, 0.f, 0.f, 0.f};
    float mrun = -INFINITY, lrun = 0.f;

    const int nkf = causal ? ((q0 + 16 + 63) >> 6) : NKST;
    const int n   = (nkf > kpar) ? ((nkf - kpar + 1) >> 1) : 0;

    // A: QK^T for head h, all 4 kt, write P (b16 halves into head-pair u32s)
    auto runA = [&](int kst) {
        const short* kbase = kb0 + (size_t)kst * 4096;
#pragma unroll
        for (int kt = 0; kt < 4; ++kt) {
            f32x4 a = (f32x4){0.f, 0.f, 0.f, 0.f};
#pragma unroll
            for (int ds = 0; ds < 2; ++ds) {
                bf16x8 kf = *reinterpret_cast<const bf16x8*>(kbase + (kt*2 + ds) * 512);
                a = __builtin_amdgcn_mfma_f32_16x16x32_bf16(qf[ds], kf, a, 0, 0, 0);
            }
#pragma unroll
            for (int rr = 0; rr < 4; ++rr) {
                int pos = (lg * 4 + rr) * 64 + kt * 16 + l15;
                reinterpret_cast<short*>(Pbuf)[pidx(pos, h >> 1) * 2 + (h & 1)] = f2bf(a[rr]);
            }
        }
    };

    bf16x8 vA = {0,0,0,0,0,0,0,0}, vB = vA;   // nt=0 V pair for the pending D

    // D: softmax + PV for step sd from M buffer Mb (uses vA/vB; loads rest)
    auto runD = [&](int sd, const int* Mb) {
        const short* vbase = vb0 + (size_t)sd * 4096;
        bf16x8 v01 = *reinterpret_cast<const bf16x8*>(vbase + 1 * 512);
        bf16x8 v11 = *reinterpret_cast<const bf16x8*>(vbase + 5 * 512);

        const int x3r = (l15 + g) & 7;
        int4 rA = *reinterpret_cast<const int4*>(&Mb[midx(g, l15 * 32 + lg * 4, x3r)]);
        int4 rB = *reinterpret_cast<const int4*>(&Mb[midx(g, l15 * 32 + 16 + lg * 4, x3r)]);

        float sm[16];
#pragma unroll
        for (int jj = 0; jj < 4; ++jj) {
            sm[2*jj]     = bflo(rA[jj]);  sm[2*jj + 1] = bfhi(rA[jj]);
            sm[8 + 2*jj] = bflo(rB[jj]);  sm[9 + 2*jj] = bfhi(rB[jj]);
        }
        if (causal && sd == nkf - 1) {
            const int k0 = sd << 6;
#pragma unroll
            for (int jj = 0; jj < 16; ++jj) {
                int kk = (jj < 8) ? (lg * 8 + jj) : (32 + lg * 8 + (jj - 8));
                if (k0 + kk > q0 + l15) sm[jj] = -INFINITY;
            }
        }

        float mx[4];
#pragma unroll
        for (int t = 0; t < 4; ++t)
            mx[t] = fmaxf(fmaxf(sm[4*t], sm[4*t+1]), fmaxf(sm[4*t+2], sm[4*t+3]));
        float mt = fmaxf(fmaxf(mx[0], mx[1]), fmaxf(mx[2], mx[3]));
        mt = fmaxf(mt, __shfl_xor(mt, 16));
        mt = fmaxf(mt, __shfl_xor(mt, 32));

        if (__any(mt > mrun + 8.0f)) {            // defer-rescale
            float mnew = fmaxf(mrun, mt);
            float scl = __builtin_amdgcn_exp2f(mrun - mnew);
            mrun = mnew;
            lrun *= scl;
            int scli = __builtin_bit_cast(int, scl);
#pragma unroll
            for (int rr = 0; rr < 4; ++rr) {
                int v = __builtin_amdgcn_ds_bpermute((lg * 4 + rr) * 4, scli);
                float s = __builtin_bit_cast(float, v);
#pragma unroll
                for (int nt = 0; nt < 4; ++nt) oacc[nt][rr] *= s;
            }
        }

        bf16x8 v02 = *reinterpret_cast<const bf16x8*>(vbase + 2 * 512);
        bf16x8 v12 = *reinterpret_cast<const bf16x8*>(vbase + 6 * 512);

#pragma unroll
        for (int jj = 0; jj < 16; ++jj) sm[jj] = __builtin_amdgcn_exp2f(sm[jj] - mrun);
        float s0 = ((sm[0]+sm[1]) + (sm[2]+sm[3])) + ((sm[4]+sm[5]) + (sm[6]+sm[7]));
        float s1 = ((sm[8]+sm[9]) + (sm[10]+sm[11])) + ((sm[12]+sm[13]) + (sm[14]+sm[15]));
        lrun += s0 + s1;

        bf16x8 v03 = *reinterpret_cast<const bf16x8*>(vbase + 3 * 512);
        bf16x8 v13 = *reinterpret_cast<const bf16x8*>(vbase + 7 * 512);

        int paw[8];
#pragma unroll
        for (int t = 0; t < 8; ++t)
            paw[t] = (int)(unsigned short)f2bf(sm[2*t]) | ((int)(unsigned short)f2bf(sm[2*t+1]) << 16);
        bf16x8 pa0 = __builtin_bit_cast(bf16x8, *(int4*)&paw[0]);
        bf16x8 pa1 = __builtin_bit_cast(bf16x8, *(int4*)&paw[4]);

        oacc[0] = __builtin_amdgcn_mfma_f32_16x16x32_bf16(pa0, vA,  oacc[0], 0, 0, 0);
        oacc[0] = __builtin_amdgcn_mfma_f32_16x16x32_bf16(pa1, vB,  oacc[0], 0, 0, 0);
        oacc[1] = __builtin_amdgcn_mfma_f32_16x16x32_bf16(pa0, v01, oacc[1], 0, 0, 0);
        oacc[1] = __builtin_amdgcn_mfma_f32_16x16x32_bf16(pa1, v11, oacc[1], 0, 0, 0);
        oacc[2] = __builtin_amdgcn_mfma_f32_16x16x32_bf16(pa0, v02, oacc[2], 0, 0, 0);
        oacc[2] = __builtin_amdgcn_mfma_f32_16x16x32_bf16(pa1, v12, oacc[2], 0, 0, 0);
        oacc[3] = __builtin_amdgcn_mfma_f32_16x16x32_bf16(pa0, v03, oacc[3], 0, 0, 0);
        oacc[3] = __builtin_amdgcn_mfma_f32_16x16x32_bf16(pa1, v13, oacc[3], 0, 0, 0);
    };

    if (n > 0) runA(kpar);   // prologue: P(s_0)

#pragma unroll 1
    for (int i = 0; i < n; ++i) {
        const int si = kpar + 2 * i;
        __syncthreads();   // b1: P(s_i) ready; M[(i-1)&1] (from iter i-1) ready

        // ---- C: head-mix MFMA for s_i -> Mbuf[i&1]; wave w owns q-row w ----
        int* Mb = &Mbuf[i & 1][0];
#pragma unroll
        for (int m = 0; m < 4; ++m) {
            const int c = w * 4 + m;
            const int pos = c * 16 + l15;
            int4 ia = {0, 0, 0, 0};
            if (lg < 2) {
                ia.x = Pbuf[pidx(pos, lg * 4 + 0)];
                ia.y = Pbuf[pidx(pos, lg * 4 + 1)];
                ia.z = Pbuf[pidx(pos, lg * 4 + 2)];
                ia.w = Pbuf[pidx(pos, lg * 4 + 3)];
            }
            bf16x8 A = __builtin_bit_cast(bf16x8, ia);
            f32x4 cc = (f32x4){0.f, 0.f, 0.f, 0.f};
            cc = __builtin_amdgcn_mfma_f32_16x16x32_bf16(A, wt, cc, 0, 0, 0);
            int loc = w * 32 + (c & 3) * 8 + lg * 2;
            int x3 = (w + l15) & 7;
            int u0 = (int)(unsigned short)f2bf(cc[0]) | ((int)(unsigned short)f2bf(cc[1]) << 16);
            int u1 = (int)(unsigned short)f2bf(cc[2]) | ((int)(unsigned short)f2bf(cc[3]) << 16);
            *reinterpret_cast<int2*>(&Mb[midx(l15, loc, x3)]) = make_int2(u0, u1);
        }

        // ---- D: softmax + PV for s_{i-1} (overlaps C's LDS + next A's VMEM) ----
        if (i > 0) runD(si - 2, &Mbuf[(i - 1) & 1][0]);

        __syncthreads();   // b2: M[i&1] ready; P free for rewrite

        // ---- A: QK^T for s_{i+1} -> P ----
        if (i + 1 < n) runA(si + 2);

        // ---- V nt=0 pair for s_i (consumed by D next iter / epilogue) ----
        {
            const short* vbase = vb0 + (size_t)si * 4096;
            vA = *reinterpret_cast<const bf16x8*>(vbase + 0 * 512);
            vB = *reinterpret_cast<const bf16x8*>(vbase + 4 * 512);
        }
    }
    if (n > 0) runD(kpar + 2 * (n - 1), &Mbuf[(n - 1) & 1][0]);

    // ---------- epilogue: normalized bf16 partial O + (m,l) ----------
    float lt = lrun;
    lt += __shfl_xor(lt, 16);
    lt += __shfl_xor(lt, 32);
    if (lg == 0)
        ppml[(((size_t)pairIdx * 2 + kpar) * 16 + g) * 16 + l15] = make_float2(mrun, lt);
    float rl = (lt > 0.f) ? (1.0f / lt) : 0.f;
    int rli = __builtin_bit_cast(int, rl);
    size_t obase = (((size_t)pairIdx * 2 + kpar) * 16 + g) * 1024;
#pragma unroll
    for (int rr = 0; rr < 4; ++rr) {
        int v = __builtin_amdgcn_ds_bpermute((lg * 4 + rr) * 4, rli);
        float linv = __builtin_bit_cast(float, v);
        int q = lg * 4 + rr;
#pragma unroll
        for (int nt = 0; nt < 4; ++nt)
            ppO[obase + q * 64 + nt * 16 + l15] =
                (unsigned short)f2bf(oacc[nt][rr] * linv);
    }
}

// ---------- combine: merge the 2 k-parity partials per (b,qt) ----------
__global__ __launch_bounds__(256) void hca_combine(
    const unsigned short* __restrict__ ppO, const float2* __restrict__ ppml,
    float* __restrict__ out)
{
    const int pairIdx = blockIdx.x;        // b*64 + qt
    const int b = pairIdx >> 6, qt = pairIdx & 63;
    const int t = threadIdx.x;
    const int g = t >> 4, dc = t & 15;

    const size_t o0 = (((size_t)pairIdx * 2 + 0) * 16 + g) * 1024;
    const size_t o1 = (((size_t)pairIdx * 2 + 1) * 16 + g) * 1024;
    const float2* ml0p = ppml + (((size_t)pairIdx * 2 + 0) * 16 + g) * 16;
    const float2* ml1p = ppml + (((size_t)pairIdx * 2 + 1) * 16 + g) * 16;

#pragma unroll 4
    for (int q = 0; q < 16; ++q) {
        float2 ml0 = ml0p[q], ml1 = ml1p[q];
        float ms = fmaxf(ml0.x, ml1.x);
        float w0 = ml0.y * exp2f(ml0.x - ms);
        float w1 = ml1.y * exp2f(ml1.x - ms);
        float rs = 1.0f / (w0 + w1);
        float a0 = w0 * rs, a1 = w1 * rs;
        ushort4 u0 = *reinterpret_cast<const ushort4*>(ppO + o0 + q * 64 + dc * 4);
        ushort4 u1 = *reinterpret_cast<const ushort4*>(ppO + o1 + q * 64 + dc * 4);
        float4 res;
        res.x = a0 * bfu(u0.x) + a1 * bfu(u1.x);
        res.y = a0 * bfu(u0.y) + a1 * bfu(u1.y);
        res.z = a0 * bfu(u0.z) + a1 * bfu(u1.z);
        res.w = a0 * bfu(u0.w) + a1 * bfu(u1.w);
        *reinterpret_cast<float4*>(out + (((size_t)b * SS + qt * 16 + q) * HH + g) * DD + dc * 4) = res;
    }
}

extern "C" void kernel_launch(void* const* d_in, const int* in_sizes, int n_in,
                              void* d_out, int out_size, void* d_ws, size_t ws_size,
                              hipStream_t stream) {
    const float* xq = (const float*)d_in[0];
    const float* xk = (const float*)d_in[1];
    const float* xv = (const float*)d_in[2];
    const float* Wm = (const float*)d_in[3];
    const int* causal = (const int*)d_in[4];
    float* out = (float*)d_out;

    short* vfr = (short*)d_ws;                               // 8 MB frag-major bf16 V
    short* kfr = vfr + (size_t)NB * HH * SS * DD;            // 8 MB frag-major bf16 K
    unsigned short* ppO = (unsigned short*)(kfr + (size_t)NB * HH * SS * DD);  // 16 MB
    float2* ppml = (float2*)(ppO + (size_t)512 * 16 * 1024); // 1 MB

    prep_all<<<2048, 256, 0, stream>>>(xk, kfr, xv, vfr);

    hca_fused<<<512, 1024, 0, stream>>>(xq, kfr, vfr, Wm, causal, ppO, ppml);
    hca_combine<<<256, 256, 0, stream>>>(ppO, ppml, out);
}

// Round 15
// 80.105 us; speedup vs baseline: 1.0054x; 1.0054x over previous
//
#include <hip/hip_runtime.h>
#include <math.h>

#define NB 4
#define HH 16
#define SS 1024
#define DD 64
#define NKST 16   // SS / 64

typedef __attribute__((ext_vector_type(8))) short bf16x8;
typedef __attribute__((ext_vector_type(4))) float f32x4;

static __device__ __forceinline__ short f2bf(float f) {
    __bf16 h = (__bf16)f;
    return __builtin_bit_cast(short, h);
}
static __device__ __forceinline__ float bflo(int w) {
    return __builtin_bit_cast(float, (unsigned)w << 16);
}
static __device__ __forceinline__ float bfhi(int w) {
    return __builtin_bit_cast(float, (unsigned)w & 0xffff0000u);
}
static __device__ __forceinline__ float bfu(unsigned short u) {
    return __builtin_bit_cast(float, (unsigned)u << 16);
}
// LDS-only barrier: waits own DS ops (reads+writes) then syncs waves, but
// does NOT drain global loads (vmcnt) -- __syncthreads() forces vmcnt(0)
// which exposed a full memory latency at every barrier (the R7-R14 wall).
// Global loads here are wave-private (K/V -> registers), so no cross-wave
// global hazard exists; P/M communication is LDS and lgkmcnt(0) covers it.
static __device__ __forceinline__ void lds_barrier() {
    asm volatile("s_waitcnt lgkmcnt(0)\n\ts_barrier" ::: "memory");
}
// P LDS: [pos = q*64 + k][8 u32 head-pairs], XOR swizzle (validated R5-R12).
static __device__ __forceinline__ int pidx(int pos, int hp) {
    int s = ((pos >> 2) & 3) | (((pos >> 9) & 1) << 2);
    return pos * 8 + (hp ^ s);
}
// M LDS: [16 g][16 q x 32 k-pairs u32], XOR on 16B groups (validated).
static __device__ __forceinline__ int midx(int g, int loc, int x3) {
    return g * 512 + ((((loc >> 2) ^ x3) << 2) | (loc & 3));
}

static __device__ __forceinline__ bf16x8 load8_bf16(const float* p) {
    const float4* p4 = reinterpret_cast<const float4*>(p);
    float4 a = p4[0], b = p4[1];
    bf16x8 f;
    f[0]=f2bf(a.x); f[1]=f2bf(a.y); f[2]=f2bf(a.z); f[3]=f2bf(a.w);
    f[4]=f2bf(b.x); f[5]=f2bf(b.y); f[6]=f2bf(b.z); f[7]=f2bf(b.w);
    return f;
}

// ---------- merged prep: LDS-staged coalesced; K and V -> frag-major bf16 ----------
__global__ __launch_bounds__(256) void prep_all(const float* __restrict__ xk,
                                                short* __restrict__ kfr,
                                                const float* __restrict__ xv,
                                                short* __restrict__ vfr) {
    __shared__ float T[64][65];
    const int bid = blockIdx.x;
    const int t = threadIdx.x;
    const bool isK = bid < 1024;
    const int tile = isK ? bid : bid - 1024;     // (b*16+h)*16 + kst
    const float* src = (isK ? xk : xv) + ((size_t)(tile >> 4) * SS + (tile & 15) * 64) * DD;
    int row = t >> 2, col = (t & 3) * 16;
#pragma unroll
    for (int ii = 0; ii < 4; ++ii) {
        float4 v = *reinterpret_cast<const float4*>(src + row * DD + col + ii * 4);
        T[row][col + ii*4] = v.x; T[row][col + ii*4 + 1] = v.y;
        T[row][col + ii*4 + 2] = v.z; T[row][col + ii*4 + 3] = v.w;
    }
    __syncthreads();
    if (isK) {
#pragma unroll
        for (int jj = 0; jj < 2; ++jj) {
            int c2 = t * 2 + jj;                  // (kt*2+ds)*64 + lane
            int lane = c2 & 63, ds = (c2 >> 6) & 1, kt = (c2 >> 7) & 3;
            bf16x8 o;
#pragma unroll
            for (int i = 0; i < 8; ++i)
                o[i] = f2bf(T[kt * 16 + (lane & 15)][ds * 32 + (lane >> 4) * 8 + i]);
            *(reinterpret_cast<bf16x8*>(kfr) + (size_t)tile * 512 + c2) = o;
        }
    } else {
#pragma unroll
        for (int jj = 0; jj < 2; ++jj) {
            int c2 = t * 2 + jj;                  // (kc*4+nt)*64 + lane
            int lane = c2 & 63, nt = (c2 >> 6) & 3, kc = (c2 >> 8) & 1;
            bf16x8 o;
#pragma unroll
            for (int i = 0; i < 8; ++i)
                o[i] = f2bf(T[kc * 32 + (lane >> 4) * 8 + i][nt * 16 + (lane & 15)]);
            *(reinterpret_cast<bf16x8*>(vfr) + (size_t)tile * 512 + c2) = o;
        }
    }
}

// One block = (b, qt, kpar), 16 waves, 64 KB LDS, 64 VGPR, grid 512 (2/CU).
// R15 = R12 with LDS-only barriers: global K/V loads stay in flight across
// sync1/sync2 instead of being drained to vmcnt(0) twice per step.
__global__ __launch_bounds__(1024) void hca_fused(
    const float* __restrict__ xq, const short* __restrict__ kfr,
    const short* __restrict__ vfr, const float* __restrict__ Wm,
    const int* __restrict__ causalp, unsigned short* __restrict__ ppO,
    float2* __restrict__ ppml)
{
    __shared__ int Pbuf[8192];   // 32 KB
    __shared__ int Mbuf[8192];   // 32 KB

    const int tid  = threadIdx.x;
    const int lane = tid & 63;
    const int w    = tid >> 6;     // 0..15
    const int l15  = lane & 15;
    const int lg   = lane >> 4;

    const int bid  = blockIdx.x;
    const int b    = bid & 3;              // b fixed per XCD
    const int u    = (bid >> 2) & 63;
    const int r    = (bid >> 8) & 1;
    const int qt   = r ? u : 63 - u;
    const int kpar = u & 1;
    const int q0   = qt << 4;
    const int pairIdx = b * 64 + qt;

    const int causal = causalp[0];
    const int hp = w & 7;          // phase-1 head pair
    const int kh = w >> 3;         // phase-1 kt half
    const int g  = w;              // phase-2 output head

    const float LOG2E = 1.44269504088896f;

    bf16x8 wt = {0,0,0,0,0,0,0,0};
    if (lg < 2) {
#pragma unroll
        for (int ii = 0; ii < 8; ++ii)
            wt[ii] = f2bf(Wm[l15 * 16 + lg * 8 + ii] * 0.125f * LOG2E);
    }

    const short* vb0 = vfr + (size_t)(b * HH + g) * NKST * 8 * 512 + lane * 8;
    const short* kb0 = kfr + (size_t)(b * HH + 2 * hp) * NKST * 8 * 512 + lane * 8;

    // Q A-frags for phase-1 heads (2hp, 2hp+1)
    bf16x8 qf[2][2];
#pragma unroll
    for (int hi = 0; hi < 2; ++hi) {
        const float* qp = xq + ((size_t)(b * HH + 2 * hp + hi) * SS + q0 + l15) * DD + lg * 8;
#pragma unroll
        for (int ds = 0; ds < 2; ++ds) qf[hi][ds] = load8_bf16(qp + ds * 32);
    }

    f32x4 oacc[4];
#pragma unroll
    for (int nt = 0; nt < 4; ++nt) oacc[nt] = (f32x4){0.f, 0.f, 0.f, 0.f};
    float mrun = -INFINITY, lrun = 0.f;

    const int nkf = causal ? ((q0 + 16 + 63) >> 6) : NKST;

#pragma unroll 1
    for (int kst = kpar; kst < nkf; kst += 2) {
        const int k0 = kst << 6;

        // ---------- phase1: QK^T heads 2hp,2hp+1, kt = 2kh, 2kh+1 ----------
        const short* kbase = kb0 + (size_t)kst * 8 * 512;
        __builtin_amdgcn_s_setprio(1);
#pragma unroll
        for (int kt2 = 0; kt2 < 2; ++kt2) {
            const int kt = kh * 2 + kt2;
            f32x4 a0 = (f32x4){0.f,0.f,0.f,0.f}, a1 = a0;
#pragma unroll
            for (int ds = 0; ds < 2; ++ds) {
                bf16x8 kfa = *reinterpret_cast<const bf16x8*>(kbase + (kt*2 + ds) * 512);
                bf16x8 kfb = *reinterpret_cast<const bf16x8*>(kbase + (NKST*8 + kt*2 + ds) * 512);
                a0 = __builtin_amdgcn_mfma_f32_16x16x32_bf16(qf[0][ds], kfa, a0, 0, 0, 0);
                a1 = __builtin_amdgcn_mfma_f32_16x16x32_bf16(qf[1][ds], kfb, a1, 0, 0, 0);
            }
#pragma unroll
            for (int rr = 0; rr < 4; ++rr) {
                int pos = (lg * 4 + rr) * 64 + kt * 16 + l15;
                int pk = (int)(unsigned short)f2bf(a0[rr]) | ((int)(unsigned short)f2bf(a1[rr]) << 16);
                Pbuf[pidx(pos, hp)] = pk;
            }
        }
        __builtin_amdgcn_s_setprio(0);

        // V prefetch: stays IN FLIGHT across both lds_barriers (no vmcnt drain);
        // consumed by PV in phase2 -> cover = mix + softmax (~2k cy).
        const short* vbase = vb0 + (size_t)kst * 8 * 512;
        bf16x8 vf[8];
#pragma unroll
        for (int kc = 0; kc < 2; ++kc)
#pragma unroll
            for (int nt = 0; nt < 4; ++nt)
                vf[kc * 4 + nt] = *reinterpret_cast<const bf16x8*>(vbase + (kc*4 + nt) * 512);

        lds_barrier();   // sync1: P ready (also fences prev phase2 M-reads)

        // ---------- phase1.5: head-mix MFMA; wave w -> q-row w ----------
#pragma unroll
        for (int m = 0; m < 4; ++m) {
            const int c = w * 4 + m;           // pos chunk; q = c>>2 = w
            const int pos = c * 16 + l15;
            int4 ia = {0, 0, 0, 0};
            if (lg < 2) {
                ia.x = Pbuf[pidx(pos, lg * 4 + 0)];
                ia.y = Pbuf[pidx(pos, lg * 4 + 1)];
                ia.z = Pbuf[pidx(pos, lg * 4 + 2)];
                ia.w = Pbuf[pidx(pos, lg * 4 + 3)];
            }
            bf16x8 A = __builtin_bit_cast(bf16x8, ia);
            f32x4 cc = (f32x4){0.f, 0.f, 0.f, 0.f};
            cc = __builtin_amdgcn_mfma_f32_16x16x32_bf16(A, wt, cc, 0, 0, 0);
            int loc = w * 32 + (c & 3) * 8 + lg * 2;
            int x3 = (w + l15) & 7;
            int u0 = (int)(unsigned short)f2bf(cc[0]) | ((int)(unsigned short)f2bf(cc[1]) << 16);
            int u1 = (int)(unsigned short)f2bf(cc[2]) | ((int)(unsigned short)f2bf(cc[3]) << 16);
            *reinterpret_cast<int2*>(&Mbuf[midx(l15, loc, x3)]) = make_int2(u0, u1);
        }
        lds_barrier();   // sync2: M ready

        // ---------- phase2: softmax (log2) + PV for head g = w ----------
        const int x3r = (l15 + g) & 7;
        int4 rA = *reinterpret_cast<const int4*>(&Mbuf[midx(g, l15 * 32 + lg * 4, x3r)]);
        int4 rB = *reinterpret_cast<const int4*>(&Mbuf[midx(g, l15 * 32 + 16 + lg * 4, x3r)]);

        float sm[16];
#pragma unroll
        for (int jj = 0; jj < 4; ++jj) {
            sm[2*jj]     = bflo(rA[jj]);  sm[2*jj + 1] = bfhi(rA[jj]);
            sm[8 + 2*jj] = bflo(rB[jj]);  sm[9 + 2*jj] = bfhi(rB[jj]);
        }
        if (causal && kst == nkf - 1) {
#pragma unroll
            for (int jj = 0; jj < 16; ++jj) {
                int kk = (jj < 8) ? (lg * 8 + jj) : (32 + lg * 8 + (jj - 8));
                if (k0 + kk > q0 + l15) sm[jj] = -INFINITY;
            }
        }

        float mx[4];
#pragma unroll
        for (int t = 0; t < 4; ++t)
            mx[t] = fmaxf(fmaxf(sm[4*t], sm[4*t+1]), fmaxf(sm[4*t+2], sm[4*t+3]));
        float mt = fmaxf(fmaxf(mx[0], mx[1]), fmaxf(mx[2], mx[3]));
        mt = fmaxf(mt, __shfl_xor(mt, 16));
        mt = fmaxf(mt, __shfl_xor(mt, 32));

        if (__any(mt > mrun + 8.0f)) {            // defer-rescale
            float mnew = fmaxf(mrun, mt);
            float scl = __builtin_amdgcn_exp2f(mrun - mnew);
            mrun = mnew;
            lrun *= scl;
            int scli = __builtin_bit_cast(int, scl);
#pragma unroll
            for (int rr = 0; rr < 4; ++rr) {
                int v = __builtin_amdgcn_ds_bpermute((lg * 4 + rr) * 4, scli);
                float s = __builtin_bit_cast(float, v);
#pragma unroll
                for (int nt = 0; nt < 4; ++nt) oacc[nt][rr] *= s;
            }
        }

#pragma unroll
        for (int jj = 0; jj < 16; ++jj) sm[jj] = __builtin_amdgcn_exp2f(sm[jj] - mrun);
        float s0 = ((sm[0]+sm[1]) + (sm[2]+sm[3])) + ((sm[4]+sm[5]) + (sm[6]+sm[7]));
        float s1 = ((sm[8]+sm[9]) + (sm[10]+sm[11])) + ((sm[12]+sm[13]) + (sm[14]+sm[15]));
        lrun += s0 + s1;

        int paw[8];
#pragma unroll
        for (int t = 0; t < 8; ++t)
            paw[t] = (int)(unsigned short)f2bf(sm[2*t]) | ((int)(unsigned short)f2bf(sm[2*t+1]) << 16);
        bf16x8 pa0 = __builtin_bit_cast(bf16x8, *(int4*)&paw[0]);
        bf16x8 pa1 = __builtin_bit_cast(bf16x8, *(int4*)&paw[4]);

        __builtin_amdgcn_s_setprio(1);
#pragma unroll
        for (int nt = 0; nt < 4; ++nt)
            oacc[nt] = __builtin_amdgcn_mfma_f32_16x16x32_bf16(pa0, vf[nt], oacc[nt], 0, 0, 0);
#pragma unroll
        for (int nt = 0; nt < 4; ++nt)
            oacc[nt] = __builtin_amdgcn_mfma_f32_16x16x32_bf16(pa1, vf[4 + nt], oacc[nt], 0, 0, 0);
        __builtin_amdgcn_s_setprio(0);
        // no trailing barrier: sync1(t+1)'s lgkmcnt(0) covers this step's
        // M-reads (ds_read completion) before next M-writes; P writes of t+1
        // are post-sync2(t) in program order for every wave.
    }

    // ---------- epilogue: normalized bf16 partial O + (m,l) ----------
    float lt = lrun;
    lt += __shfl_xor(lt, 16);
    lt += __shfl_xor(lt, 32);
    if (lg == 0)
        ppml[(((size_t)pairIdx * 2 + kpar) * 16 + g) * 16 + l15] = make_float2(mrun, lt);
    float rl = (lt > 0.f) ? (1.0f / lt) : 0.f;
    int rli = __builtin_bit_cast(int, rl);
    size_t obase = (((size_t)pairIdx * 2 + kpar) * 16 + g) * 1024;
#pragma unroll
    for (int rr = 0; rr < 4; ++rr) {
        int v = __builtin_amdgcn_ds_bpermute((lg * 4 + rr) * 4, rli);
        float linv = __builtin_bit_cast(float, v);
        int q = lg * 4 + rr;
#pragma unroll
        for (int nt = 0; nt < 4; ++nt)
            ppO[obase + q * 64 + nt * 16 + l15] =
                (unsigned short)f2bf(oacc[nt][rr] * linv);
    }
}

// ---------- combine: merge the 2 k-parity partials per (b,qt) ----------
__global__ __launch_bounds__(256) void hca_combine(
    const unsigned short* __restrict__ ppO, const float2* __restrict__ ppml,
    float* __restrict__ out)
{
    const int pairIdx = blockIdx.x;        // b*64 + qt
    const int b = pairIdx >> 6, qt = pairIdx & 63;
    const int t = threadIdx.x;
    const int g = t >> 4, dc = t & 15;

    const size_t o0 = (((size_t)pairIdx * 2 + 0) * 16 + g) * 1024;
    const size_t o1 = (((size_t)pairIdx * 2 + 1) * 16 + g) * 1024;
    const float2* ml0p = ppml + (((size_t)pairIdx * 2 + 0) * 16 + g) * 16;
    const float2* ml1p = ppml + (((size_t)pairIdx * 2 + 1) * 16 + g) * 16;

#pragma unroll 4
    for (int q = 0; q < 16; ++q) {
        float2 ml0 = ml0p[q], ml1 = ml1p[q];
        float ms = fmaxf(ml0.x, ml1.x);
        float w0 = ml0.y * exp2f(ml0.x - ms);
        float w1 = ml1.y * exp2f(ml1.x - ms);
        float rs = 1.0f / (w0 + w1);
        float a0 = w0 * rs, a1 = w1 * rs;
        ushort4 u0 = *reinterpret_cast<const ushort4*>(ppO + o0 + q * 64 + dc * 4);
        ushort4 u1 = *reinterpret_cast<const ushort4*>(ppO + o1 + q * 64 + dc * 4);
        float4 res;
        res.x = a0 * bfu(u0.x) + a1 * bfu(u1.x);
        res.y = a0 * bfu(u0.y) + a1 * bfu(u1.y);
        res.z = a0 * bfu(u0.z) + a1 * bfu(u1.z);
        res.w = a0 * bfu(u0.w) + a1 * bfu(u1.w);
        *reinterpret_cast<float4*>(out + (((size_t)b * SS + qt * 16 + q) * HH + g) * DD + dc * 4) = res;
    }
}

extern "C" void kernel_launch(void* const* d_in, const int* in_sizes, int n_in,
                              void* d_out, int out_size, void* d_ws, size_t ws_size,
                              hipStream_t stream) {
    const float* xq = (const float*)d_in[0];
    const float* xk = (const float*)d_in[1];
    const float* xv = (const float*)d_in[2];
    const float* Wm = (const float*)d_in[3];
    const int* causal = (const int*)d_in[4];
    float* out = (float*)d_out;

    short* vfr = (short*)d_ws;                               // 8 MB frag-major bf16 V
    short* kfr = vfr + (size_t)NB * HH * SS * DD;            // 8 MB frag-major bf16 K
    unsigned short* ppO = (unsigned short*)(kfr + (size_t)NB * HH * SS * DD);  // 16 MB
    float2* ppml = (float2*)(ppO + (size_t)512 * 16 * 1024); // 1 MB

    prep_all<<<2048, 256, 0, stream>>>(xk, kfr, xv, vfr);

    hca_fused<<<512, 1024, 0, stream>>>(xq, kfr, vfr, Wm, causal, ppO, ppml);
    hca_combine<<<256, 256, 0, stream>>>(ppO, ppml, out);
}